// Round 1
// baseline (713.709 us; speedup 1.0000x reference)
//
#include <hip/hip_runtime.h>

#define NX 512
#define NY 512
#define NZ 256

__global__ __launch_bounds__(256) void trilerp_kernel(
    const float* __restrict__ x,
    const float* __restrict__ grid,
    const float* __restrict__ lower,
    const float* __restrict__ resolution,
    float* __restrict__ out,
    int n)
{
    int i = blockIdx.x * blockDim.x + threadIdx.x;
    if (i >= n) return;

    float px = x[3 * i + 0];
    float py = x[3 * i + 1];
    float pz = x[3 * i + 2];

    // Uniform scalars (L1/L2-cached; compiler scalarizes the uniform loads)
    float lx = lower[0], ly = lower[1], lz = lower[2];
    float rx = resolution[0], ry = resolution[1], rz = resolution[2];

    float fx = (px - lx) * rx;
    float fy = (py - ly) * ry;
    float fz = (pz - lz) * rz;

    bool valid = (fx >= 0.0f) && (fx <= (float)(NX - 1)) &&
                 (fy >= 0.0f) && (fy <= (float)(NY - 1)) &&
                 (fz >= 0.0f) && (fz <= (float)(NZ - 1));

    float sigma = 0.0f, alpha = 0.0f;

    if (valid) {
        float cfx = floorf(fx), cfy = floorf(fy), cfz = floorf(fz);
        float wx = fx - cfx, wy = fy - cfy, wz = fz - cfz;

        int ix0 = (int)cfx, iy0 = (int)cfy, iz0 = (int)cfz;
        int ix1 = min(ix0 + 1, NX - 1);
        int iy1 = min(iy0 + 1, NY - 1);
        int iz1 = min(iz0 + 1, NZ - 1);

        // grid element (ix,iy,iz) as float2 (sigma, alpha): flat index (ix*NY+iy)*NZ+iz
        const float2* __restrict__ g = (const float2*)grid;

        int b00 = (ix0 * NY + iy0) * NZ;
        int b01 = (ix0 * NY + iy1) * NZ;
        int b10 = (ix1 * NY + iy0) * NZ;
        int b11 = (ix1 * NY + iy1) * NZ;

        float2 v000 = g[b00 + iz0];
        float2 v001 = g[b00 + iz1];
        float2 v010 = g[b01 + iz0];
        float2 v011 = g[b01 + iz1];
        float2 v100 = g[b10 + iz0];
        float2 v101 = g[b10 + iz1];
        float2 v110 = g[b11 + iz0];
        float2 v111 = g[b11 + iz1];

        float ux = 1.0f - wx, uy = 1.0f - wy, uz = 1.0f - wz;

        float w000 = ux * uy * uz;
        float w001 = ux * uy * wz;
        float w010 = ux * wy * uz;
        float w011 = ux * wy * wz;
        float w100 = wx * uy * uz;
        float w101 = wx * uy * wz;
        float w110 = wx * wy * uz;
        float w111 = wx * wy * wz;

        sigma = w000 * v000.x + w001 * v001.x + w010 * v010.x + w011 * v011.x +
                w100 * v100.x + w101 * v101.x + w110 * v110.x + w111 * v111.x;
        alpha = w000 * v000.y + w001 * v001.y + w010 * v010.y + w011 * v011.y +
                w100 * v100.y + w101 * v101.y + w110 * v110.y + w111 * v111.y;
    }

    out[i] = sigma;
    out[n + i] = alpha;
}

extern "C" void kernel_launch(void* const* d_in, const int* in_sizes, int n_in,
                              void* d_out, int out_size, void* d_ws, size_t ws_size,
                              hipStream_t stream) {
    const float* x          = (const float*)d_in[0];
    const float* grid       = (const float*)d_in[1];
    const float* lower      = (const float*)d_in[2];
    const float* resolution = (const float*)d_in[3];
    float* out              = (float*)d_out;

    int n = in_sizes[0] / 3;  // x is [N,3]

    int block = 256;
    int blocks = (n + block - 1) / block;
    trilerp_kernel<<<blocks, block, 0, stream>>>(x, grid, lower, resolution, out, n);
}